// Round 1
// 83.314 us; speedup vs baseline: 1.3326x; 1.3326x over previous
//
#include <hip/hip_runtime.h>
#include <hip/hip_bf16.h>

#define SEQN 2048
#define SEQM 2048
#define CDIM 256
#define NB   4
#define NH   4

using bf16x8 = __attribute__((ext_vector_type(8))) short;
using f32x4  = __attribute__((ext_vector_type(4))) float;

__device__ inline unsigned short f2bf(float x) {
    __hip_bfloat16 h = __float2bfloat16(x);
    return *reinterpret_cast<unsigned short*>(&h);
}

// ---------------------------------------------------------------------------
// Fused prep: all mutually-independent preprocessing in ONE launch.
//   blocks [0,4)            : compact kv_mask -> pidx/mcnt
//   blocks [4,516)          : fold Wmh+BN into W1 -> Acat/cvec
//   blocks [516,836)        : cast Wq/Wk/Wv/W2 fp32->bf16
//   blocks [836,1860)       : transpose+cast x1->catT (512), x2->x2T (512)
// ---------------------------------------------------------------------------
__global__ __launch_bounds__(256) void prep_k(
    const int* __restrict__ kvm, int* __restrict__ pidx, int* __restrict__ mcnt,
    const float* __restrict__ W1, const float* __restrict__ b1,
    const float* __restrict__ gamma, const float* __restrict__ beta,
    const float* __restrict__ mean, const float* __restrict__ var,
    const float* __restrict__ Wmh, const float* __restrict__ bmh,
    unsigned short* __restrict__ Acat, float* __restrict__ cvec,
    const float* __restrict__ Wq, const float* __restrict__ Wk,
    const float* __restrict__ Wv, const float* __restrict__ W2,
    unsigned short* __restrict__ Wqb, unsigned short* __restrict__ Wkb,
    unsigned short* __restrict__ Wvb, unsigned short* __restrict__ W2b,
    const float* __restrict__ x1, const float* __restrict__ x2,
    unsigned short* __restrict__ catT, unsigned short* __restrict__ x2T)
{
    __shared__ float smemf[64 * 68];
    const int bid = blockIdx.x, tid = threadIdx.x;

    if (bid < NB) {
        // ---- compact mask: pidx[m] = packed position (or -1), mcnt = count
        int* sc = reinterpret_cast<int*>(smemf);
        const int b = bid;
        int loc[8], c = 0;
        #pragma unroll
        for (int e = 0; e < 8; ++e) {
            loc[e] = (kvm[(size_t)b * SEQM + tid * 8 + e] != 0) ? 1 : 0;
            c += loc[e];
        }
        sc[tid] = c;
        __syncthreads();
        for (int off = 1; off < 256; off <<= 1) {
            int v = (tid >= off) ? sc[tid - off] : 0;
            __syncthreads();
            sc[tid] += v;
            __syncthreads();
        }
        int p = sc[tid] - c;
        if (tid == 255) mcnt[b] = sc[255];
        #pragma unroll
        for (int e = 0; e < 8; ++e) {
            pidx[(size_t)b * SEQM + tid * 8 + e] = loc[e] ? p : -1;
            p += loc[e];
        }
    } else if (bid < NB + 512) {
        // ---- fold Wmh + BatchNorm into W1 -> Acat bf16 [512][512], cvec
        const int j = bid - NB;    // 0..511
        const int c = tid;         // 0..255
        const float s = gamma[j] * rsqrtf(var[j] + 1e-5f);
        const float* w1b = W1 + (size_t)j * 512 + 256;
        Acat[(size_t)j * 512 + c] = f2bf(s * W1[(size_t)j * 512 + c]);
        float acc = 0.f;
        for (int t = 0; t < 256; ++t)
            acc += w1b[t] * Wmh[(size_t)t * 256 + c];
        Acat[(size_t)j * 512 + 256 + c] = f2bf(s * acc);
        if (c == 0) {
            float ab = 0.f;
            for (int t = 0; t < 256; ++t) ab += w1b[t] * bmh[t];
            cvec[j] = s * (b1[j] + ab - mean[j]) + beta[j];
        }
    } else if (bid < NB + 512 + 320) {
        // ---- weight casts fp32 -> bf16
        int cid = bid - (NB + 512);
        const float* src; unsigned short* dst; int n;
        if (cid < 64)       { src = Wq; dst = Wqb; n = 65536; }
        else if (cid < 128) { src = Wk; dst = Wkb; n = 65536;  cid -= 64;  }
        else if (cid < 192) { src = Wv; dst = Wvb; n = 65536;  cid -= 128; }
        else                { src = W2; dst = W2b; n = 131072; cid -= 192; }
        const int idx = (cid * 256 + tid) * 4;
        if (idx < n) {
            float4 v = *reinterpret_cast<const float4*>(&src[idx]);
            ushort4 p; p.x = f2bf(v.x); p.y = f2bf(v.y); p.z = f2bf(v.z); p.w = f2bf(v.w);
            *reinterpret_cast<ushort4*>(&dst[idx]) = p;
        }
    } else {
        // ---- fp32 [b][256][2048] -> bf16 [b*2048][ldd], 64x64 LDS transpose
        int t = bid - (NB + 512 + 320);
        const float* src; unsigned short* dst; int ldd;
        if (t < 512) { src = x1; dst = catT; ldd = 512; }
        else         { src = x2; dst = x2T;  ldd = 256; t -= 512; }
        const int cx = t & 3, ny = (t >> 2) & 31, b = t >> 7;
        const int c0 = cx * 64, n0 = ny * 64;
        float (*Ts)[68] = reinterpret_cast<float(*)[68]>(smemf);
        const int cr = tid >> 2, nc = (tid & 3) * 16;
        #pragma unroll
        for (int q = 0; q < 4; ++q) {
            float4 v = *reinterpret_cast<const float4*>(
                &src[((size_t)b * CDIM + c0 + cr) * SEQN + n0 + nc + 4 * q]);
            *reinterpret_cast<float4*>(&Ts[cr][nc + 4 * q]) = v;
        }
        __syncthreads();
        const int nr = tid >> 2, cc = (tid & 3) * 16;
        unsigned short tmp[16];
        #pragma unroll
        for (int e = 0; e < 16; ++e) tmp[e] = f2bf(Ts[cc + e][nr]);
        unsigned short* dp = &dst[((size_t)(b * SEQN + n0 + nr)) * ldd + c0 + cc];
        #pragma unroll
        for (int q = 0; q < 4; ++q)
            *reinterpret_cast<ushort4*>(&dp[4 * q]) = *reinterpret_cast<ushort4*>(&tmp[4 * q]);
    }
}

// ---------------------------------------------------------------------------
// Fused Q/K/V projection GEMMs in one launch (grid.z selects which).
// Same 128x64 tile / BK=64 / 4-wave main loop as gemm_mfma_k; per-z epilogue:
//   z=0: Q -> qbf [b][h][n][d], scaled, dense rows
//   z=1: K -> kbf [b][h][pos][d], pidx row-scatter
//   z=2: V -> vbf [b][o][pos], pidx col-scatter
// ---------------------------------------------------------------------------
__global__ __launch_bounds__(256) void qkv_gemm_k(
    const unsigned short* __restrict__ Wqb, const unsigned short* __restrict__ Wkb,
    const unsigned short* __restrict__ Wvb,
    const unsigned short* __restrict__ catT, const unsigned short* __restrict__ x2T,
    const float* __restrict__ bq, const float* __restrict__ bk,
    const float* __restrict__ bv,
    unsigned short* __restrict__ qbf, unsigned short* __restrict__ kbf,
    unsigned short* __restrict__ vbf,
    const int* __restrict__ pidx, float qscale)
{
    __shared__ short At[128][72];
    __shared__ short Bt[64][72];
    const int z = blockIdx.z;
    const unsigned short* W = (z == 0) ? Wqb : (z == 1) ? Wkb : Wvb;
    const unsigned short* X = (z == 0) ? catT : x2T;
    const float* bias = (z == 0) ? bq : (z == 1) ? bk : bv;
    const int ldx = (z == 0) ? 512 : 256;

    const int tid = threadIdx.x;
    const int w = tid >> 6, l = tid & 63, lm = l & 15, lg = l >> 4;
    const int o0 = blockIdx.x * 128, ng0 = blockIdx.y * 64;
    const int wo = (w >> 1) * 64, wn = (w & 1) * 32;

    f32x4 acc[4][2] = {};
    const int arow = tid >> 2, acol = (tid & 3) * 16;

    for (int k0 = 0; k0 < 256; k0 += 64) {
        __syncthreads();
        #pragma unroll
        for (int p = 0; p < 2; ++p) {
            const unsigned short* s = &W[(size_t)(o0 + arow + 64 * p) * 256 + k0 + acol];
            *reinterpret_cast<bf16x8*>(&At[arow + 64 * p][acol]) =
                *reinterpret_cast<const bf16x8*>(s);
            *reinterpret_cast<bf16x8*>(&At[arow + 64 * p][acol + 8]) =
                *reinterpret_cast<const bf16x8*>(s + 8);
        }
        {
            const unsigned short* s = &X[(size_t)(ng0 + arow) * ldx + k0 + acol];
            *reinterpret_cast<bf16x8*>(&Bt[arow][acol]) =
                *reinterpret_cast<const bf16x8*>(s);
            *reinterpret_cast<bf16x8*>(&Bt[arow][acol + 8]) =
                *reinterpret_cast<const bf16x8*>(s + 8);
        }
        __syncthreads();
        #pragma unroll
        for (int kc = 0; kc < 2; ++kc) {
            bf16x8 a[4], bf[2];
            #pragma unroll
            for (int i = 0; i < 4; ++i)
                a[i] = *reinterpret_cast<const bf16x8*>(&At[wo + 16 * i + lm][kc * 32 + lg * 8]);
            #pragma unroll
            for (int j = 0; j < 2; ++j)
                bf[j] = *reinterpret_cast<const bf16x8*>(&Bt[wn + 16 * j + lm][kc * 32 + lg * 8]);
            #pragma unroll
            for (int i = 0; i < 4; ++i)
                #pragma unroll
                for (int j = 0; j < 2; ++j)
                    acc[i][j] = __builtin_amdgcn_mfma_f32_16x16x32_bf16(a[i], bf[j], acc[i][j], 0, 0, 0);
        }
    }

    #pragma unroll
    for (int j = 0; j < 2; ++j) {
        const int ng = ng0 + wn + 16 * j + lm;
        const int b = ng >> 11, n = ng & 2047;
        const int pos = (z == 0) ? n : pidx[(size_t)b * SEQM + n];
        #pragma unroll
        for (int i = 0; i < 4; ++i) {
            const int ob = o0 + wo + 16 * i + 4 * lg;
            float4 bv4 = *reinterpret_cast<const float4*>(&bias[ob]);
            float v[4] = {acc[i][j][0] + bv4.x, acc[i][j][1] + bv4.y,
                          acc[i][j][2] + bv4.z, acc[i][j][3] + bv4.w};
            if (z == 2) {
                if (pos >= 0) {
                    #pragma unroll
                    for (int r = 0; r < 4; ++r)
                        vbf[((size_t)b * CDIM + ob + r) * SEQM + pos] = f2bf(v[r]);
                }
            } else if (pos >= 0) {
                const int hh = ob >> 6, dbase = ob & 63;
                const float sc_ = (z == 0) ? qscale : 1.0f;
                ushort4 pk;
                pk.x = f2bf(v[0] * sc_); pk.y = f2bf(v[1] * sc_);
                pk.z = f2bf(v[2] * sc_); pk.w = f2bf(v[3] * sc_);
                unsigned short* dst = (z == 0) ? qbf : kbf;
                *reinterpret_cast<ushort4*>(
                    &dst[(((size_t)b * NH + hh) * SEQN + pos) * 64 + dbase]) = pk;
            }
        }
    }
}

// ---------------------------------------------------------------------------
// bf16 MFMA GEMM (modes 2/3 used): C[o][ng] = W[o][:] @ X[ng][:]
// OMODE 2: bf16 [ng][512] bias+ReLU (hidden)   3: fp32 [b][o][n] bias+res
// ---------------------------------------------------------------------------
template<int OMODE>
__global__ __launch_bounds__(256) void gemm_mfma_k(
    const unsigned short* __restrict__ W, const unsigned short* __restrict__ X,
    const float* __restrict__ bias, const float* __restrict__ res,
    unsigned short* __restrict__ obf, float* __restrict__ ofp,
    const int* __restrict__ pidx, int K, int ldx, float oscale)
{
    __shared__ short At[128][72];
    __shared__ short Bt[64][72];
    const int tid = threadIdx.x;
    const int w = tid >> 6, l = tid & 63, lm = l & 15, lg = l >> 4;
    const int o0 = blockIdx.x * 128, ng0 = blockIdx.y * 64;
    const int wo = (w >> 1) * 64, wn = (w & 1) * 32;

    f32x4 acc[4][2] = {};
    const int arow = tid >> 2, acol = (tid & 3) * 16;

    for (int k0 = 0; k0 < K; k0 += 64) {
        __syncthreads();
        #pragma unroll
        for (int p = 0; p < 2; ++p) {
            const unsigned short* s = &W[(size_t)(o0 + arow + 64 * p) * K + k0 + acol];
            *reinterpret_cast<bf16x8*>(&At[arow + 64 * p][acol]) =
                *reinterpret_cast<const bf16x8*>(s);
            *reinterpret_cast<bf16x8*>(&At[arow + 64 * p][acol + 8]) =
                *reinterpret_cast<const bf16x8*>(s + 8);
        }
        {
            const unsigned short* s = &X[(size_t)(ng0 + arow) * ldx + k0 + acol];
            *reinterpret_cast<bf16x8*>(&Bt[arow][acol]) =
                *reinterpret_cast<const bf16x8*>(s);
            *reinterpret_cast<bf16x8*>(&Bt[arow][acol + 8]) =
                *reinterpret_cast<const bf16x8*>(s + 8);
        }
        __syncthreads();
        #pragma unroll
        for (int kc = 0; kc < 2; ++kc) {
            bf16x8 a[4], bf[2];
            #pragma unroll
            for (int i = 0; i < 4; ++i)
                a[i] = *reinterpret_cast<const bf16x8*>(&At[wo + 16 * i + lm][kc * 32 + lg * 8]);
            #pragma unroll
            for (int j = 0; j < 2; ++j)
                bf[j] = *reinterpret_cast<const bf16x8*>(&Bt[wn + 16 * j + lm][kc * 32 + lg * 8]);
            #pragma unroll
            for (int i = 0; i < 4; ++i)
                #pragma unroll
                for (int j = 0; j < 2; ++j)
                    acc[i][j] = __builtin_amdgcn_mfma_f32_16x16x32_bf16(a[i], bf[j], acc[i][j], 0, 0, 0);
        }
    }

    #pragma unroll
    for (int j = 0; j < 2; ++j) {
        const int ng = ng0 + wn + 16 * j + lm;
        const int b = ng >> 11, n = ng & 2047;
        #pragma unroll
        for (int i = 0; i < 4; ++i) {
            const int ob = o0 + wo + 16 * i + 4 * lg;
            float4 bv = *reinterpret_cast<const float4*>(&bias[ob]);
            float v[4] = {acc[i][j][0] + bv.x, acc[i][j][1] + bv.y,
                          acc[i][j][2] + bv.z, acc[i][j][3] + bv.w};
            if (OMODE == 2) {
                ushort4 pk;
                pk.x = f2bf(fmaxf(v[0], 0.f)); pk.y = f2bf(fmaxf(v[1], 0.f));
                pk.z = f2bf(fmaxf(v[2], 0.f)); pk.w = f2bf(fmaxf(v[3], 0.f));
                *reinterpret_cast<ushort4*>(&obf[(size_t)ng * 512 + ob]) = pk;
            } else {
                #pragma unroll
                for (int r = 0; r < 4; ++r) {
                    size_t ad = ((size_t)b * CDIM + ob + r) * SEQN + n;
                    ofp[ad] = v[r] + res[ad];
                }
            }
        }
    }
}

// ---------------------------------------------------------------------------
// MFMA flash attention over PACKED K/V (valid columns only, mcnt per batch).
// Swapped-QK^T, dbuf, issue-early/write-late, XOR-swizzled LDS, v_perm pack.
// ---------------------------------------------------------------------------
__global__ __launch_bounds__(256) void attn_mfma_k(
    const unsigned short* __restrict__ qbf, const unsigned short* __restrict__ kbf,
    const unsigned short* __restrict__ vbf, const int* __restrict__ mcntg,
    unsigned short* __restrict__ catT)
{
    __shared__ short Ks[2][64][64];        // [buf][pos][d], swizzled cols
    __shared__ short Vs[2][64][64];        // [buf][d][pos], swizzled cols
    __shared__ unsigned int Ps[4][16][36]; // per-wave P pairs [n][pos/2]

    const int tid = threadIdx.x;
    const int w = tid >> 6, l = tid & 63;
    const int lm = l & 15, lg = l >> 4;
    const int h = blockIdx.y, b = blockIdx.z;
    const int n_base = blockIdx.x * 64 + w * 16;
    const size_t bhN = (size_t)(b * NH + h) * SEQN;
    const size_t cBase = (size_t)b * CDIM + h * 64;

    const int mcnt = mcntg[b];
    const int ntiles = (mcnt + 63) >> 6;

    if (ntiles == 0) {
        #pragma unroll
        for (int r = 0; r < 4; ++r) {
            int n = n_base + 4 * lg + r;
            unsigned short* dst = &catT[((size_t)b * SEQN + n) * 512 + 256 + h * 64];
            #pragma unroll
            for (int t = 0; t < 4; ++t) dst[16 * t + lm] = 0;
        }
        return;
    }

    const size_t qrow = (bhN + n_base + lm) * 64;
    bf16x8 qa0 = *reinterpret_cast<const bf16x8*>(&qbf[qrow + lg * 8]);
    bf16x8 qa1 = *reinterpret_cast<const bf16x8*>(&qbf[qrow + 32 + lg * 8]);

    f32x4 oacc[4] = {};
    float mrun = -3.0e5f, lrun = 0.f;

    const int r0 = tid >> 3, c8 = (tid & 7) * 8;
    const int c8s = c8 ^ ((r0 & 7) << 3);
    const int colr0 = (lg * 8) ^ ((lm & 7) << 3);
    const int colr1 = (32 + lg * 8) ^ ((lm & 7) << 3);

    {
        bf16x8 kr[2], vr[2];
        #pragma unroll
        for (int p = 0; p < 2; ++p) {
            kr[p] = *reinterpret_cast<const bf16x8*>(&kbf[(bhN + r0 + 32 * p) * 64 + c8]);
            vr[p] = *reinterpret_cast<const bf16x8*>(&vbf[(cBase + r0 + 32 * p) * SEQM + c8]);
        }
        #pragma unroll
        for (int p = 0; p < 2; ++p) {
            *reinterpret_cast<bf16x8*>(&Ks[0][r0 + 32 * p][c8s]) = kr[p];
            *reinterpret_cast<bf16x8*>(&Vs[0][r0 + 32 * p][c8s]) = vr[p];
        }
    }
    __syncthreads();

    for (int t64 = 0; t64 < ntiles; ++t64) {
        const int cur = t64 & 1;
        const bool has_next = (t64 < ntiles - 1);
        const int m0n = (t64 + 1) * 64;

        bf16x8 kr[2], vr[2];
        if (has_next) {
            #pragma unroll
            for (int p = 0; p < 2; ++p) {
                kr[p] = *reinterpret_cast<const bf16x8*>(
                    &kbf[(bhN + m0n + r0 + 32 * p) * 64 + c8]);
                vr[p] = *reinterpret_cast<const bf16x8*>(
                    &vbf[(cBase + r0 + 32 * p) * SEQM + m0n + c8]);
            }
        }

        f32x4 sv[4];
        __builtin_amdgcn_s_setprio(1);
        #pragma unroll
        for (int t = 0; t < 4; ++t) {
            bf16x8 ka0 = *reinterpret_cast<const bf16x8*>(&Ks[cur][16 * t + lm][colr0]);
            bf16x8 ka1 = *reinterpret_cast<const bf16x8*>(&Ks[cur][16 * t + lm][colr1]);
            f32x4 z = {0.f, 0.f, 0.f, 0.f};
            z = __builtin_amdgcn_mfma_f32_16x16x32_bf16(ka0, qa0, z, 0, 0, 0);
            z = __builtin_amdgcn_mfma_f32_16x16x32_bf16(ka1, qa1, z, 0, 0, 0);
            sv[t] = z;
        }
        __builtin_amdgcn_s_setprio(0);

        float mx = fmaxf(fmaxf(fmaxf(sv[0][0], sv[0][1]), fmaxf(sv[0][2], sv[0][3])),
                         fmaxf(fmaxf(sv[1][0], sv[1][1]), fmaxf(sv[1][2], sv[1][3])));
        mx = fmaxf(mx, fmaxf(fmaxf(fmaxf(sv[2][0], sv[2][1]), fmaxf(sv[2][2], sv[2][3])),
                             fmaxf(fmaxf(sv[3][0], sv[3][1]), fmaxf(sv[3][2], sv[3][3]))));
        mx = fmaxf(mx, __shfl_xor(mx, 16));
        mx = fmaxf(mx, __shfl_xor(mx, 32));
        const bool grew = (mx > mrun);
        float mnew = fmaxf(mrun, mx);
        float scl = exp2f(mrun - mnew);
        mrun = mnew;

        float rsum = 0.f;
        const int mrem = mcnt - t64 * 64;
        if (mrem >= 64) {
            #pragma unroll
            for (int t = 0; t < 4; ++t) {
                float p0 = exp2f(sv[t][0] - mnew);
                float p1 = exp2f(sv[t][1] - mnew);
                float p2 = exp2f(sv[t][2] - mnew);
                float p3 = exp2f(sv[t][3] - mnew);
                rsum += (p0 + p1) + (p2 + p3);
                unsigned int u0 = __builtin_amdgcn_perm(
                    __float_as_uint(p1), __float_as_uint(p0), 0x07060302u);
                unsigned int u1 = __builtin_amdgcn_perm(
                    __float_as_uint(p3), __float_as_uint(p2), 0x07060302u);
                *reinterpret_cast<uint2*>(&Ps[w][lm][8 * t + 2 * lg]) = make_uint2(u0, u1);
            }
        } else {
            #pragma unroll
            for (int t = 0; t < 4; ++t) {
                const int mb = 16 * t + 4 * lg;
                float p0 = (mb + 0 < mrem) ? exp2f(sv[t][0] - mnew) : 0.f;
                float p1 = (mb + 1 < mrem) ? exp2f(sv[t][1] - mnew) : 0.f;
                float p2 = (mb + 2 < mrem) ? exp2f(sv[t][2] - mnew) : 0.f;
                float p3 = (mb + 3 < mrem) ? exp2f(sv[t][3] - mnew) : 0.f;
                rsum += (p0 + p1) + (p2 + p3);
                unsigned int u0 = __builtin_amdgcn_perm(
                    __float_as_uint(p1), __float_as_uint(p0), 0x07060302u);
                unsigned int u1 = __builtin_amdgcn_perm(
                    __float_as_uint(p3), __float_as_uint(p2), 0x07060302u);
                *reinterpret_cast<uint2*>(&Ps[w][lm][8 * t + 2 * lg]) = make_uint2(u0, u1);
            }
        }
        rsum += __shfl_xor(rsum, 16);
        rsum += __shfl_xor(rsum, 32);
        lrun = lrun * scl + rsum;

        if (__any(grew && scl < 1.f)) {
            float sr[4];
            #pragma unroll
            for (int r = 0; r < 4; ++r) sr[r] = __shfl(scl, 4 * lg + r);
            #pragma unroll
            for (int t = 0; t < 4; ++t)
                #pragma unroll
                for (int r = 0; r < 4; ++r)
                    oacc[t][r] *= sr[r];
        }

        bf16x8 pa0 = *reinterpret_cast<const bf16x8*>(&Ps[w][lm][4 * lg]);
        bf16x8 pa1 = *reinterpret_cast<const bf16x8*>(&Ps[w][lm][16 + 4 * lg]);
        __builtin_amdgcn_s_setprio(1);
        #pragma unroll
        for (int t = 0; t < 4; ++t) {
            bf16x8 vb0 = *reinterpret_cast<const bf16x8*>(&Vs[cur][16 * t + lm][colr0]);
            bf16x8 vb1 = *reinterpret_cast<const bf16x8*>(&Vs[cur][16 * t + lm][colr1]);
            oacc[t] = __builtin_amdgcn_mfma_f32_16x16x32_bf16(pa0, vb0, oacc[t], 0, 0, 0);
            oacc[t] = __builtin_amdgcn_mfma_f32_16x16x32_bf16(pa1, vb1, oacc[t], 0, 0, 0);
        }
        __builtin_amdgcn_s_setprio(0);

        if (has_next) {
            const int nxt = cur ^ 1;
            #pragma unroll
            for (int p = 0; p < 2; ++p) {
                *reinterpret_cast<bf16x8*>(&Ks[nxt][r0 + 32 * p][c8s]) = kr[p];
                *reinterpret_cast<bf16x8*>(&Vs[nxt][r0 + 32 * p][c8s]) = vr[p];
            }
        }
        __syncthreads();
    }

    #pragma unroll
    for (int r = 0; r < 4; ++r) {
        float rinv = 1.f / __shfl(lrun, 4 * lg + r);
        int n = n_base + 4 * lg + r;
        unsigned short* dst = &catT[((size_t)b * SEQN + n) * 512 + 256 + h * 64];
        #pragma unroll
        for (int t = 0; t < 4; ++t)
            dst[16 * t + lm] = f2bf(oacc[t][r] * rinv);
    }
}

// ---------------------------------------------------------------------------
extern "C" void kernel_launch(void* const* d_in, const int* in_sizes, int n_in,
                              void* d_out, int out_size, void* d_ws, size_t ws_size,
                              hipStream_t stream)
{
    (void)in_sizes; (void)n_in; (void)out_size; (void)ws_size;
    const float* x1    = (const float*)d_in[0];
    const float* x2    = (const float*)d_in[1];
    const int*   kvm   = (const int*)  d_in[2];
    const float* Wq    = (const float*)d_in[3];
    const float* bq    = (const float*)d_in[4];
    const float* Wk    = (const float*)d_in[5];
    const float* bk    = (const float*)d_in[6];
    const float* Wv    = (const float*)d_in[7];
    const float* bv    = (const float*)d_in[8];
    const float* Wmh   = (const float*)d_in[9];
    const float* bmh   = (const float*)d_in[10];
    const float* W1    = (const float*)d_in[11];
    const float* b1    = (const float*)d_in[12];
    const float* gamma = (const float*)d_in[13];
    const float* beta  = (const float*)d_in[14];
    const float* mean  = (const float*)d_in[15];
    const float* var   = (const float*)d_in[16];
    const float* W2    = (const float*)d_in[17];
    const float* b2    = (const float*)d_in[18];
    float* out = (float*)d_out;

    const size_t act = (size_t)NB * CDIM * SEQN;        // 2,097,152
    unsigned short* ws   = (unsigned short*)d_ws;
    unsigned short* qbf  = ws;                 // act
    unsigned short* kbf  = qbf  + act;         // act
    unsigned short* vbf  = kbf  + act;         // act
    unsigned short* x2T  = vbf  + act;         // act
    unsigned short* catT = x2T  + act;         // 8192*512
    unsigned short* hbuf = catT + 2 * act;     // 8192*512
    unsigned short* Wqb  = hbuf + 2 * act;     // 65536
    unsigned short* Wkb  = Wqb  + 65536;
    unsigned short* Wvb  = Wkb  + 65536;
    unsigned short* W2b  = Wvb  + 65536;       // 131072
    unsigned short* Acat = W2b  + 131072;      // 262144
    float*          cvec = (float*)(Acat + 262144);
    int*            pidx = (int*)(cvec + 512);          // NB*2048
    int*            mcnt = pidx + (size_t)NB * SEQM;    // NB

    const float qscale = 0.125f * 1.44269504088896f;   // fold 1/sqrt(D)*log2(e)

    // 1) all independent prep in one launch (compact ∥ fuse ∥ casts ∥ transposes)
    prep_k<<<dim3(NB + 512 + 320 + 1024), dim3(256), 0, stream>>>(
        kvm, pidx, mcnt,
        W1, b1, gamma, beta, mean, var, Wmh, bmh, Acat, cvec,
        Wq, Wk, Wv, W2, Wqb, Wkb, Wvb, W2b,
        x1, x2, catT, x2T);

    // 2) Q ∥ K ∥ V projections in one launch
    qkv_gemm_k<<<dim3(2, 128, 3), dim3(256), 0, stream>>>(
        Wqb, Wkb, Wvb, catT, x2T, bq, bk, bv, qbf, kbf, vbf, pidx, qscale);

    // 3) flash attention over packed K/V
    attn_mfma_k<<<dim3(SEQN / 64, NH, NB), dim3(256), 0, stream>>>(
        qbf, kbf, vbf, mcnt, catT);

    // 4) hidden = relu(Acat @ cat + cvec)
    gemm_mfma_k<2><<<dim3(4, 128), dim3(256), 0, stream>>>(
        Acat, catT, cvec, nullptr, hbuf, nullptr, nullptr, 512, 512, 1.0f);

    // 5) out = x1 + W2 @ hidden + b2
    gemm_mfma_k<3><<<dim3(2, 128), dim3(256), 0, stream>>>(
        W2b, hbuf, b2, x1, nullptr, out, nullptr, 512, 512, 1.0f);
}